// Round 13
// baseline (8670.345 us; speedup 1.0000x reference)
//
#include <hip/hip_runtime.h>
#include <cstdint>

constexpr int Bn = 128, Tn = 1024, Dn = 64, Hn = 256, On = 128;

typedef __fp16 h2 __attribute__((ext_vector_type(2)));
typedef __fp16 half8_t __attribute__((ext_vector_type(8)));
typedef float f32x4 __attribute__((ext_vector_type(4)));
typedef unsigned short u16;

__device__ __forceinline__ float fast_tanh(float x) {
  float e = __expf(2.0f * x);
  return 1.0f - 2.0f / (e + 1.0f);
}
__device__ __forceinline__ h2 pk2(float a, float b) {
  h2 r; r.x = (__fp16)a; r.y = (__fp16)b; return r;
}
__device__ __forceinline__ unsigned h2bits(h2 v) { return __builtin_bit_cast(unsigned, v); }
__device__ __forceinline__ u16 f2hb(float f) {
  __fp16 h = (__fp16)f; return __builtin_bit_cast(u16, h);
}
__device__ __forceinline__ float hb2f(u16 b) {
  return (float)__builtin_bit_cast(__fp16, b);
}

// ---------------------------------------------------------------------------
// 4-chain MFMA matvec, K=256, source in the 20-stride slice layout.
// A-frag is the BROADCAST trick (rounds 10/11, absmax-verified): every lane's
// af covers k = 32kt + 8*(l>>4) + e, independent of l&15 -> all 16 rows of A
// equal h -> D reg 0 = h @ W for every lane. A and B use the SAME assumed
// k-map so any intra-tile k-permutation cancels.
// Weights: 32 half8_t frags = 128 regs -> AGPR file (MFMA reads natively).
// ---------------------------------------------------------------------------
__device__ __forceinline__ void mv256(const u16* base, int oh, int ol,
                                      const half8_t (&wf)[32], float (&v)[4]) {
  uint2 ra[8], rb[8];
  #pragma unroll
  for (int kt = 0; kt < 8; ++kt) {
    const u16* ap = base + 40 * kt + 20 * oh + 8 * ol;
    ra[kt] = *(const uint2*)ap;
    rb[kt] = *(const uint2*)(ap + 4);
  }
  f32x4 a0 = {0.f,0.f,0.f,0.f}, a1 = {0.f,0.f,0.f,0.f},
        a2 = {0.f,0.f,0.f,0.f}, a3 = {0.f,0.f,0.f,0.f};
  #pragma unroll
  for (int kt = 0; kt < 8; ++kt) {
    half8_t af = __builtin_bit_cast(
        half8_t, make_uint4(ra[kt].x, ra[kt].y, rb[kt].x, rb[kt].y));
    a0 = __builtin_amdgcn_mfma_f32_16x16x32_f16(af, wf[kt], a0, 0, 0, 0);
    a1 = __builtin_amdgcn_mfma_f32_16x16x32_f16(af, wf[8 + kt], a1, 0, 0, 0);
    a2 = __builtin_amdgcn_mfma_f32_16x16x32_f16(af, wf[16 + kt], a2, 0, 0, 0);
    a3 = __builtin_amdgcn_mfma_f32_16x16x32_f16(af, wf[24 + kt], a3, 0, 0, 0);
  }
  v[0] = a0[0]; v[1] = a1[0]; v[2] = a2[0]; v[3] = a3[0];
}
// K=64 variant; source row in plain stride-64-half layout, 16B aligned.
// Uses wf[g*8 + kt], kt in {0,1}.
__device__ __forceinline__ void mv64(const u16* xrow, int lq,
                                     const half8_t (&wf)[32], float (&v)[4]) {
  uint4 r0 = *(const uint4*)(xrow + lq);
  uint4 r1 = *(const uint4*)(xrow + 32 + lq);
  half8_t af0 = __builtin_bit_cast(half8_t, r0);
  half8_t af1 = __builtin_bit_cast(half8_t, r1);
  f32x4 a0 = {0.f,0.f,0.f,0.f}, a1 = {0.f,0.f,0.f,0.f},
        a2 = {0.f,0.f,0.f,0.f}, a3 = {0.f,0.f,0.f,0.f};
  a0 = __builtin_amdgcn_mfma_f32_16x16x32_f16(af0, wf[0], a0, 0, 0, 0);
  a0 = __builtin_amdgcn_mfma_f32_16x16x32_f16(af1, wf[1], a0, 0, 0, 0);
  a1 = __builtin_amdgcn_mfma_f32_16x16x32_f16(af0, wf[8], a1, 0, 0, 0);
  a1 = __builtin_amdgcn_mfma_f32_16x16x32_f16(af1, wf[9], a1, 0, 0, 0);
  a2 = __builtin_amdgcn_mfma_f32_16x16x32_f16(af0, wf[16], a2, 0, 0, 0);
  a2 = __builtin_amdgcn_mfma_f32_16x16x32_f16(af1, wf[17], a2, 0, 0, 0);
  a3 = __builtin_amdgcn_mfma_f32_16x16x32_f16(af0, wf[24], a3, 0, 0, 0);
  a3 = __builtin_amdgcn_mfma_f32_16x16x32_f16(af1, wf[25], a3, 0, 0, 0);
  v[0] = a0[0]; v[1] = a1[0]; v[2] = a2[0]; v[3] = a3[0];
}

// LDS h layout (f16): 16 slices x (16 data + 4 pad) halfs; slice stride 40 B.
// ---------------------------------------------------------------------------
// Fused pipeline, 256 WGs x 512 threads (8 waves). Round-12/13 thesis: the
// serial-step cost tracks BARRIER POPULATION, not compute path (16-wave
// variants: 1.05-1.15 us/step across v_dot/MFMA/AGPR/scratch; 8-wave round-0
// structures: 0.61-0.78). So: 8-wave blocks, wave-specialized:
//   waves 0-3 serial (64 cols each via 4 MFMA chains; W frags in AGPR),
//   waves 4-7 dense  (u-rows via the same MFMA matvec; row s+1 in slice s).
// (512,2): 256 unified regs/wave -- the known-good regime (rounds 4/5:
// VGPR=104, no spill), NOT the 1024-thr 64-arch ceiling. No inline asm.
//   role A  (blocks 0..127):  serial scan1 (Wh1) + dense u1 = x@Wx1+b1.
//   role BC (blocks 128..255): serial scan2 (Wh2) + dense u2 = h1@Wx2+b2.
// ROUND-13 FIX: BC h1 staging reverted to round-11's verified pattern (512
// slice-tasks, 2 per thread). Round 12's 256-thread variant loaded only 16
// of each thread's 32 columns and scattered them across slices -> absmax
// 4.4e-2. Everything else unchanged from round 12.
// ---------------------------------------------------------------------------
__global__ __launch_bounds__(512, 2) void stage1_kernel(
    const float* __restrict__ x,    // [B,T,64] f32
    const float* __restrict__ Wx1,  // [64,256] f32
    const float* __restrict__ Wh1,  // [256,256] f32
    const float* __restrict__ b1,   // [256]
    const float* __restrict__ Wx2,  // [256,256] f32
    const float* __restrict__ b2,   // [256]
    const float* __restrict__ Wh2,  // [256,256] f32
    u16* __restrict__ h1b16,        // [B,T,256] f16 h1 (A -> BC channel)
    int* __restrict__ flags,        // [B]  A -> BC progress (32-step chunks)
    float* __restrict__ hfinal) {   // [B,256] f32 (role BC output)
  __shared__ alignas(16) u16 smemU[19584];  // 38.25 KB
  const int tid = threadIdx.x;
  const unsigned bid = blockIdx.x;
  const bool roleA = (bid < (unsigned)Bn);
  const int wv = tid >> 6;              // wave 0..7
  const bool serialG = (wv < 4);
  const int l = tid & 63;
  const int oh = (l >> 5) & 1;
  const int ol = (l >> 4) & 1;
  const int lq = 8 * (l >> 4);          // k-oct offset (halfs)
  const int c0 = 64 * (wv & 3);         // wave's column base
  const int lt = tid & 255;             // index within wave-group

  // ---- weights: col c0+16g+(l&15), k = 32kt + lq + e ----
  half8_t wf[32];
  {
    const float* Wsrc = roleA ? (serialG ? Wh1 : Wx1)
                              : (serialG ? Wh2 : Wx2);
    const int kmax = (roleA && !serialG) ? 2 : 8;
    for (int g = 0; g < 4; ++g)
      for (int kt = 0; kt < kmax; ++kt) {
        const float* wp =
            Wsrc + (size_t)(32 * kt + lq) * Hn + c0 + 16 * g + (l & 15);
        half8_t f;
        #pragma unroll
        for (int e = 0; e < 8; ++e) f[e] = (__fp16)wp[(size_t)e * Hn];
        wf[g * 8 + kt] = f;
      }
  }

  if (roleA) {
    // ==================== ROLE A ====================
    const int b = bid;
    const float* xb = x + (size_t)b * Tn * Dn;
    u16* hb = h1b16 + (size_t)b * Tn * Hn;
    u16* hcH = smemU;            // 640 halfs: 2 x 320 h-state
    u16* xs = smemU + 640;       // 2048 halfs: x chunk [32][64] f16
    u16* u1S = smemU + 2688;     // 8704 halfs: u1 [32][272]
    float bj[4];
    if (!serialG) {
      #pragma unroll
      for (int g = 0; g < 4; ++g) bj[g] = b1[c0 + 16 * g + (l & 15)];
    }
    for (int i = tid; i < 640; i += 512) hcH[i] = 0;
    __syncthreads();

    for (int ch = 0; ch < 32; ++ch) {
      if (!serialG) {  // stage x chunk -> xs (f16): thread -> 8 f32
        const float* src = xb + (size_t)ch * 2048 + lt * 8;
        float4 f0 = *(const float4*)src, f1 = *(const float4*)(src + 4);
        *(uint4*)(xs + lt * 8) =
            make_uint4(h2bits(pk2(f0.x, f0.y)), h2bits(pk2(f0.z, f0.w)),
                       h2bits(pk2(f1.x, f1.y)), h2bits(pk2(f1.z, f1.w)));
      }
      __syncthreads();
      if (!serialG) {  // u1 row 0
        float v[4];
        mv64(xs, lq, wf, v);
        if (l < 16) {
          #pragma unroll
          for (int g = 0; g < 4; ++g)
            u1S[c0 + 16 * g + l] = f2hb(v[g] + bj[g]);
        }
      }
      __syncthreads();
      for (int g4 = 0; g4 < 4; ++g4) {
        u16 hr[4][8];
        #pragma unroll
        for (int s8 = 0; s8 < 8; ++s8) {
          const int s = 8 * g4 + s8;
          if (serialG) {
            const int cu = s & 1, nx = cu ^ 1;
            float uv[4];
            #pragma unroll
            for (int g = 0; g < 4; ++g)
              uv[g] = hb2f(u1S[s * 272 + c0 + 16 * g + (l & 15)]);
            float v[4];
            mv256(hcH + cu * 320, oh, ol, wf, v);
            #pragma unroll
            for (int g = 0; g < 4; ++g) {
              u16 hh = f2hb(fast_tanh(v[g] + uv[g]));
              if (l < 16) hcH[nx * 320 + 20 * (4 * wv + g) + l] = hh;
              hr[g][s8] = hh;
            }
            if (s8 == 7 && l < 16) {
              u16* d0 = hb + (size_t)(ch * 32 + 8 * g4) * Hn + c0 + l;
              #pragma unroll
              for (int i = 0; i < 8; ++i)
                #pragma unroll
                for (int g = 0; g < 4; ++g) d0[i * Hn + 16 * g] = hr[g][i];
            }
          } else if (s < 31) {
            float v[4];
            mv64(xs + (s + 1) * 64, lq, wf, v);
            if (l < 16) {
              #pragma unroll
              for (int g = 0; g < 4; ++g)
                u1S[(s + 1) * 272 + c0 + 16 * g + l] = f2hb(v[g] + bj[g]);
            }
          }
          __syncthreads();  // drains vmem (incl. h1 stores at s8==7)
        }
      }
      if (tid == 0)
        __hip_atomic_store(flags + b, ch + 1, __ATOMIC_RELEASE,
                           __HIP_MEMORY_SCOPE_AGENT);
    }
  } else {
    // ==================== ROLE BC ====================
    const int b = bid - Bn;
    const u16* hb1 = h1b16 + (size_t)b * Tn * Hn;
    u16* hsH = smemU;            // [32][320] halfs (h1 staging, slice layout)
    u16* u2S = smemU + 10240;    // [32][272] halfs (u2)
    u16* hcU = smemU + 18944;    // 2 x 320 halfs (h2 state)
    float bj[4];
    if (!serialG) {
      #pragma unroll
      for (int g = 0; g < 4; ++g) bj[g] = b2[c0 + 16 * g + (l & 15)];
    }
    for (int i = tid; i < 640; i += 512) hcU[i] = 0;
    __syncthreads();

    for (int ch = 0; ch < 32; ++ch) {
      if (!serialG && lt == 0) {
        while (__hip_atomic_load(flags + b, __ATOMIC_ACQUIRE,
                                 __HIP_MEMORY_SCOPE_AGENT) < ch + 1)
          __builtin_amdgcn_s_sleep(8);
      }
      __syncthreads();  // flag acquired
      if (!serialG) {
        // stage h1 chunk -> hsH, round-11-verified pattern: 512 slice-tasks
        // (row 0..31 x slice 0..15), 2 per dense thread. Each task: 16 halfs
        // from global row into slice sc of the 20-stride layout.
        #pragma unroll
        for (int it = 0; it < 2; ++it) {
          const int idx = lt + 256 * it;        // 0..511
          const int row = idx >> 4, sc = idx & 15;
          const u16* src = hb1 + (size_t)(ch * 32 + row) * Hn + 16 * sc;
          uint4 v0 = ((const uint4*)src)[0], v1 = ((const uint4*)src)[1];
          u16* d = hsH + row * 320 + 20 * sc;
          ((uint2*)d)[0] = make_uint2(v0.x, v0.y);
          ((uint2*)d)[1] = make_uint2(v0.z, v0.w);
          ((uint2*)d)[2] = make_uint2(v1.x, v1.y);
          ((uint2*)d)[3] = make_uint2(v1.z, v1.w);
        }
      }
      __syncthreads();  // staged
      if (!serialG) {   // u2 row 0
        float v[4];
        mv256(hsH, oh, ol, wf, v);
        if (l < 16) {
          #pragma unroll
          for (int g = 0; g < 4; ++g)
            u2S[c0 + 16 * g + l] = f2hb(v[g] + bj[g]);
        }
      }
      __syncthreads();  // row 0 visible

      for (int g4 = 0; g4 < 4; ++g4) {
        #pragma unroll
        for (int s8 = 0; s8 < 8; ++s8) {
          const int s = 8 * g4 + s8;
          if (serialG) {
            const int cu = s & 1, nx = cu ^ 1;
            float uv[4];
            #pragma unroll
            for (int g = 0; g < 4; ++g)
              uv[g] = hb2f(u2S[s * 272 + c0 + 16 * g + (l & 15)]);
            float v[4];
            mv256(hcU + cu * 320, oh, ol, wf, v);
            #pragma unroll
            for (int g = 0; g < 4; ++g) {
              u16 hh = f2hb(fast_tanh(v[g] + uv[g]));
              if (l < 16) hcU[nx * 320 + 20 * (4 * wv + g) + l] = hh;
            }
          } else if (s < 31) {
            float v[4];
            mv256(hsH + (s + 1) * 320, oh, ol, wf, v);
            if (l < 16) {
              #pragma unroll
              for (int g = 0; g < 4; ++g)
                u2S[(s + 1) * 272 + c0 + 16 * g + l] = f2hb(v[g] + bj[g]);
            }
          }
          __syncthreads();
        }
      }
    }
    if (tid < Hn)
      hfinal[(size_t)b * Hn + tid] = hb2f(hcU[(tid >> 4) * 20 + (tid & 15)]);
  }
}

// ---------------------------------------------------------------------------
// Head: out = softmax(h2_T @ Wd + bd). f32, unchanged.
// ---------------------------------------------------------------------------
__global__ __launch_bounds__(128) void head_kernel(
    const float* __restrict__ hfinal, const float* __restrict__ Wd,
    const float* __restrict__ bd, float* __restrict__ out) {
  __shared__ float hrow[Hn];
  __shared__ float red[On];
  const int o = threadIdx.x;
  const int b = blockIdx.x;
  hrow[o] = hfinal[(size_t)b * Hn + o];
  hrow[o + 128] = hfinal[(size_t)b * Hn + 128 + o];
  __syncthreads();
  float acc = bd[o];
  #pragma unroll 8
  for (int k = 0; k < Hn; ++k) acc = fmaf(hrow[k], Wd[(size_t)k * On + o], acc);
  red[o] = acc;
  __syncthreads();
  #pragma unroll
  for (int s = 64; s > 0; s >>= 1) {
    if (o < s) red[o] = fmaxf(red[o], red[o + s]);
    __syncthreads();
  }
  const float mx = red[0];
  __syncthreads();
  const float e = __expf(acc - mx);
  red[o] = e;
  __syncthreads();
  #pragma unroll
  for (int s = 64; s > 0; s >>= 1) {
    if (o < s) red[o] += red[o + s];
    __syncthreads();
  }
  out[(size_t)b * On + o] = e / red[0];
}

// ---------------------------------------------------------------------------
extern "C" void kernel_launch(void* const* d_in, const int* in_sizes, int n_in,
                              void* d_out, int out_size, void* d_ws, size_t ws_size,
                              hipStream_t stream) {
  const float* x   = (const float*)d_in[0];
  const float* Wx1 = (const float*)d_in[1];
  const float* Wh1 = (const float*)d_in[2];
  const float* b1  = (const float*)d_in[3];
  const float* Wx2 = (const float*)d_in[4];
  const float* Wh2 = (const float*)d_in[5];
  const float* b2  = (const float*)d_in[6];
  const float* Wd  = (const float*)d_in[7];
  const float* bd  = (const float*)d_in[8];
  float* out = (float*)d_out;

  u16* h1b16 = (u16*)d_ws;                            // [B,T,256] f16 (64 MB)
  float* hfinal = (float*)(h1b16 + (size_t)Bn * Tn * Hn);  // [B,256] f32
  int* flags = (int*)(hfinal + (size_t)Bn * Hn);      // [B] A->BC

  hipMemsetAsync(flags, 0, Bn * sizeof(int), stream);
  stage1_kernel<<<2 * Bn, 512, 0, stream>>>(x, Wx1, Wh1, b1, Wx2, b2, Wh2,
                                            h1b16, flags, hfinal);
  head_kernel<<<Bn, 128, 0, stream>>>(hfinal, Wd, bd, out);
}